// Round 11
// baseline (158.376 us; speedup 1.0000x reference)
//
#include <hip/hip_runtime.h>
#include <hip/hip_bf16.h>

typedef __attribute__((ext_vector_type(8))) short short8;
typedef __attribute__((ext_vector_type(8))) unsigned short ushort8;
typedef __attribute__((ext_vector_type(4))) float floatx4;
typedef __attribute__((ext_vector_type(16))) float floatx16;
typedef __attribute__((ext_vector_type(4))) unsigned int uint4v;
typedef __attribute__((ext_vector_type(2))) unsigned int uint2v;

#define DEVINL static __device__ __forceinline__

DEVINL float b2f(unsigned short s){ union{unsigned u; float f;} v; v.u=((unsigned)s)<<16; return v.f; }
DEVINL unsigned fbits(float f){ union{float f; unsigned u;} v; v.f=f; return v.u; }
DEVINL unsigned pack2(float f0, float f1){
  return __builtin_amdgcn_perm(fbits(f1)+0x8000u, fbits(f0)+0x8000u, 0x07060302u);
}
// single-instruction packed cvt (RNE), gfx950
DEVINL unsigned cvt_pk(float lo, float hi){
  unsigned r;
  asm("v_cvt_pk_bf16_f32 %0, %1, %2" : "=v"(r) : "v"(lo), "v"(hi));
  return r;
}
// tanh(x) = 1 - 2/(1+e^{2x}); exact limits at +-inf
DEVINL float tanh_fast(float v){
  float ex = __builtin_amdgcn_exp2f(v * 2.885390081777927f);   // e^{2v}
  return 1.f - 2.f*__builtin_amdgcn_rcpf(1.f + ex);
}

constexpr int Sc=256, Hc=768, Nc=128, HIDc=1024, Lc=16;

// ================= merged prep kernel =================
__global__ __launch_bounds__(256) void k_prep(const float* __restrict__ AH,
                                              const int* __restrict__ ST,
                                              const float* __restrict__ W1,
                                              const float* __restrict__ W2,
                                              unsigned short* __restrict__ con,
                                              unsigned short* __restrict__ w1mF,
                                              unsigned short* __restrict__ w2F2,
                                              unsigned short* __restrict__ wPQF){
  int bid = blockIdx.x, t = threadIdx.x;
  if (bid < 512) {
    int row = bid;                      // b*128 + n
    int b = row >> 7;
    int st = ST[row];
    const float* src = AH + ((size_t)(b*Sc + st))*Hc;
    unsigned short* dst = con + (size_t)row*Hc;
    if (t < 192) {
      float4 v = reinterpret_cast<const float4*>(src)[t];
      uint2v o = { pack2(v.x, v.y), pack2(v.z, v.w) };
      *reinterpret_cast<uint2v*>(dst + 4*t) = o;
    }
  } else if (bid < 896) {
    int sid = (bid - 512)*256 + t;      // 0..98303
    int l = sid & 63, kc = (sid >> 6) % 48, ht = sid / (48*64);
    int k = kc*16 + (l >> 5)*8;
    int h = ht*32 + (l & 31);
    const float* wp = W1 + (size_t)(2304 + k)*1024 + h;
    uint4v d;
    d[0] = pack2(wp[0],      wp[1024]);
    d[1] = pack2(wp[2*1024], wp[3*1024]);
    d[2] = pack2(wp[4*1024], wp[5*1024]);
    d[3] = pack2(wp[6*1024], wp[7*1024]);
    *reinterpret_cast<uint4v*>(w1mF + (size_t)sid*8) = d;
  } else if (bid < 912) {
    int gid = (bid - 896)*256 + t;      // 0..4095
    int l = gid & 63, chunk = gid >> 6;
    int row = l & 31, s = l >> 5;
    unsigned u[4];
    #pragma unroll
    for (int p = 0; p < 4; ++p) {
      int e0 = 2*p, e1 = 2*p + 1;
      int h0 = chunk*16 + 4*s + (e0 & 3) + 8*(e0 >> 2);
      int h1 = chunk*16 + 4*s + (e1 & 3) + 8*(e1 >> 2);
      float v0 = (row < 16) ? W2[(size_t)h0*Lc + row] : 0.f;
      float v1 = (row < 16) ? W2[(size_t)h1*Lc + row] : 0.f;
      u[p] = pack2(v0, v1);
    }
    uint4v d = { u[0], u[1], u[2], u[3] };
    *reinterpret_cast<uint4v*>(w2F2 + (size_t)gid*8) = d;
  } else {
    int sid = (bid - 912)*256 + t;      // 0..196607
    int lane = sid & 63, kcq = (sid >> 6) % 24, ht = sid / (24*64);
    int col = lane & 15, seg = lane >> 4;
    int hp = ht*16 + col;
    int kb = kcq*32 + seg*8;
    uint4v d;
    if (hp < 1024) {
      const float* w0 = W1 + (size_t)kb*1024 + hp;
      const float* wd = W1 + (size_t)(1536+kb)*1024 + hp;
      d[0] = pack2(w0[0]+wd[0],           w0[1024]+wd[1024]);
      d[1] = pack2(w0[2*1024]+wd[2*1024], w0[3*1024]+wd[3*1024]);
      d[2] = pack2(w0[4*1024]+wd[4*1024], w0[5*1024]+wd[5*1024]);
      d[3] = pack2(w0[6*1024]+wd[6*1024], w0[7*1024]+wd[7*1024]);
    } else {
      int hq = hp - 1024;
      const float* wc = W1 + (size_t)(768+kb)*1024 + hq;
      const float* wd = W1 + (size_t)(1536+kb)*1024 + hq;
      d[0] = pack2(wc[0]-wd[0],           wc[1024]-wd[1024]);
      d[1] = pack2(wc[2*1024]-wd[2*1024], wc[3*1024]-wd[3*1024]);
      d[2] = pack2(wc[4*1024]-wd[4*1024], wc[5*1024]-wd[5*1024]);
      d[3] = pack2(wc[6*1024]-wd[6*1024], wc[7*1024]-wd[7*1024]);
    }
    *reinterpret_cast<uint4v*>(wPQF + (size_t)sid*8) = d;
  }
}

// ---------------- P/Q via MFMA: out[512 rows][2048 cols] ----------------
__global__ __launch_bounds__(256) void k_pq(const unsigned short* __restrict__ con,
                                            const unsigned short* __restrict__ wPQF,
                                            float* __restrict__ P, float* __restrict__ Q){
  int rg = blockIdx.x >> 4, hg = blockIdx.x & 15;     // 16 rowgroups x 16 colgroups
  int t = threadIdx.x, w = t >> 6, lane = t & 63;
  int colh = lane & 15, rseg = lane >> 4;
  floatx4 zero = {0.f,0.f,0.f,0.f};
  floatx4 acc[2][2] = {{zero,zero},{zero,zero}};
  const unsigned short* a0p = con + (size_t)(rg*32 + colh)*Hc + rseg*8;
  const unsigned short* a1p = a0p + 16*Hc;
  const unsigned short* b0p = wPQF + (((size_t)((hg*8 + w*2)*24)) << 9) + (lane << 3);
  const unsigned short* b1p = b0p + (24 << 9);
  #pragma unroll
  for (int kc = 0; kc < 24; ++kc) {
    short8 af0 = *reinterpret_cast<const short8*>(a0p + kc*32);
    short8 af1 = *reinterpret_cast<const short8*>(a1p + kc*32);
    short8 bf0 = *reinterpret_cast<const short8*>(b0p + ((size_t)kc << 9));
    short8 bf1 = *reinterpret_cast<const short8*>(b1p + ((size_t)kc << 9));
    acc[0][0] = __builtin_amdgcn_mfma_f32_16x16x32_bf16(af0, bf0, acc[0][0], 0,0,0);
    acc[0][1] = __builtin_amdgcn_mfma_f32_16x16x32_bf16(af0, bf1, acc[0][1], 0,0,0);
    acc[1][0] = __builtin_amdgcn_mfma_f32_16x16x32_bf16(af1, bf0, acc[1][0], 0,0,0);
    acc[1][1] = __builtin_amdgcn_mfma_f32_16x16x32_bf16(af1, bf1, acc[1][1], 0,0,0);
  }
  #pragma unroll
  for (int m = 0; m < 2; ++m)
    #pragma unroll
    for (int n = 0; n < 2; ++n)
      #pragma unroll
      for (int rr = 0; rr < 4; ++rr) {
        int row = rg*32 + m*16 + rseg*4 + rr;
        int hp = hg*128 + w*32 + n*16 + colh;
        float val = acc[m][n][rr];
        if (hg < 8) P[(size_t)row*HIDc + hp] = val;
        else        Q[(size_t)row*HIDc + (hp - 1024)] = val;
      }
}

// ---------------- fused main kernel ----------------
// r10 + : BK=64 rounds (1 barrier per 64-k, 12 rounds/hc), setprio(1) around
// the 16-MFMA cluster, XCD-bijective block swizzle (each XCD owns one (b,jh):
// w1mF+con+Q slice ~2.1MB fits its private L2).
__global__ __launch_bounds__(256, 2) void k_main(const unsigned short* __restrict__ con,
    const unsigned short* __restrict__ w1mF, const unsigned short* __restrict__ w2F2,
    const float* __restrict__ P, const float* __restrict__ Q, const float* __restrict__ b1,
    const float* __restrict__ b2v, float* __restrict__ out){
  __shared__ float a_row[768];
  __shared__ float Pi_lds[1024];
  __shared__ __align__(16) unsigned short A_lds[2][8][64][8];   // dbuf x (4 ksub x 2 jt)
  __shared__ __align__(16) float red[16][64][4];                // 16KB reduce buf

  // XCD-bijective decode: 1024 = 8 XCDs x 128 blocks; XCD owns one (b,jh)
  int bid = blockIdx.x;
  int xcd = bid & 7, idx = bid >> 3;
  int b = xcd >> 1, jh = xcd & 1, i = idx;
  int bi = b*128 + i, bN = b*128;
  int t = threadIdx.x, w = t >> 6, lane = t & 63;
  int col32 = lane & 31, hi5 = lane >> 5;

  // staging role: thread t stages ksub slotL and slotL+2, j-tile jtA, lane t&63
  int slotL = t >> 7, jtA = (t >> 6) & 1;
  int jstage = jh*64 + jtA*32 + col32;
  int koffA0 = slotL*16 + hi5*8;           // within 64-k round
  int koffA1 = koffA0 + 32;
  const unsigned short* conA = con + (size_t)(bN + jstage)*Hc;
  unsigned short* AwrA[2] = { &A_lds[0][slotL*2 + jtA][t & 63][0],
                              &A_lds[1][slotL*2 + jtA][t & 63][0] };
  unsigned short* AwrB[2] = { &A_lds[0][(slotL+2)*2 + jtA][t & 63][0],
                              &A_lds[1][(slotL+2)*2 + jtA][t & 63][0] };

  if (t < 96) {
    ushort8 c8 = *reinterpret_cast<const ushort8*>(con + (size_t)(bN + i)*Hc + t*8);
    #pragma unroll
    for (int e = 0; e < 8; ++e) a_row[t*8 + e] = b2f((unsigned short)c8[e]);
  }
  {
    float4 p4 = reinterpret_cast<const float4*>(P + (size_t)(bN + i)*HIDc)[t];
    float4 b4 = reinterpret_cast<const float4*>(b1)[t];
    float4 s4 = { p4.x + b4.x, p4.y + b4.y, p4.z + b4.z, p4.w + b4.w };
    *reinterpret_cast<float4*>(&Pi_lds[4*t]) = s4;
  }

  floatx16 acc2_0, acc2_1;
  #pragma unroll
  for (int r = 0; r < 16; ++r) { acc2_0[r] = 0.f; acc2_1[r] = 0.f; }
  __syncthreads();

// load ca (global, 2x ushort8) + av (LDS, 4x floatx4) for 64-k round R
#define LOADCA(R) { \
  caN0 = *reinterpret_cast<const ushort8*>(conA + (R)*64 + koffA0); \
  caN1 = *reinterpret_cast<const ushort8*>(conA + (R)*64 + koffA1); }
#define LOADAV(R) { \
  avN0 = *reinterpret_cast<const floatx4*>(&a_row[(R)*64 + koffA0]); \
  avN1 = *reinterpret_cast<const floatx4*>(&a_row[(R)*64 + koffA0 + 4]); \
  avN2 = *reinterpret_cast<const floatx4*>(&a_row[(R)*64 + koffA1]); \
  avN3 = *reinterpret_cast<const floatx4*>(&a_row[(R)*64 + koffA1 + 4]); }
#define PACKW2(BUF) { \
  uint4v dA_; \
  dA_[0] = cvt_pk(avN0[0]*b2f(caN0[0]), avN0[1]*b2f(caN0[1])); \
  dA_[1] = cvt_pk(avN0[2]*b2f(caN0[2]), avN0[3]*b2f(caN0[3])); \
  dA_[2] = cvt_pk(avN1[0]*b2f(caN0[4]), avN1[1]*b2f(caN0[5])); \
  dA_[3] = cvt_pk(avN1[2]*b2f(caN0[6]), avN1[3]*b2f(caN0[7])); \
  *reinterpret_cast<uint4v*>(AwrA[BUF]) = dA_; \
  dA_[0] = cvt_pk(avN2[0]*b2f(caN1[0]), avN2[1]*b2f(caN1[1])); \
  dA_[1] = cvt_pk(avN2[2]*b2f(caN1[2]), avN2[3]*b2f(caN1[3])); \
  dA_[2] = cvt_pk(avN3[0]*b2f(caN1[4]), avN3[1]*b2f(caN1[5])); \
  dA_[3] = cvt_pk(avN3[2]*b2f(caN1[6]), avN3[3]*b2f(caN1[7])); \
  *reinterpret_cast<uint4v*>(AwrB[BUF]) = dA_; }
// load 8 wx fragments (2 ht x 4 ksub) for 64-k round R
#define LOADWX8(R) { \
  wx0a = *reinterpret_cast<const ushort8*>(w1p0 + (((size_t)((R)*4 + 0)) << 9)); \
  wx1a = *reinterpret_cast<const ushort8*>(w1p0 + (((size_t)((R)*4 + 1)) << 9)); \
  wx2a = *reinterpret_cast<const ushort8*>(w1p0 + (((size_t)((R)*4 + 2)) << 9)); \
  wx3a = *reinterpret_cast<const ushort8*>(w1p0 + (((size_t)((R)*4 + 3)) << 9)); \
  wx0b = *reinterpret_cast<const ushort8*>(w1p1 + (((size_t)((R)*4 + 0)) << 9)); \
  wx1b = *reinterpret_cast<const ushort8*>(w1p1 + (((size_t)((R)*4 + 1)) << 9)); \
  wx2b = *reinterpret_cast<const ushort8*>(w1p1 + (((size_t)((R)*4 + 2)) << 9)); \
  wx3b = *reinterpret_cast<const ushort8*>(w1p1 + (((size_t)((R)*4 + 3)) << 9)); }
#define MFMA16(BUF) { \
  short8 y0 = *reinterpret_cast<const short8*>(&A_lds[BUF][0][lane][0]); \
  short8 y1 = *reinterpret_cast<const short8*>(&A_lds[BUF][1][lane][0]); \
  short8 y2 = *reinterpret_cast<const short8*>(&A_lds[BUF][2][lane][0]); \
  short8 y3 = *reinterpret_cast<const short8*>(&A_lds[BUF][3][lane][0]); \
  short8 y4 = *reinterpret_cast<const short8*>(&A_lds[BUF][4][lane][0]); \
  short8 y5 = *reinterpret_cast<const short8*>(&A_lds[BUF][5][lane][0]); \
  short8 y6 = *reinterpret_cast<const short8*>(&A_lds[BUF][6][lane][0]); \
  short8 y7 = *reinterpret_cast<const short8*>(&A_lds[BUF][7][lane][0]); \
  __builtin_amdgcn_s_setprio(1); \
  acc00 = __builtin_amdgcn_mfma_f32_32x32x16_bf16(wx0a, y0, acc00, 0,0,0); \
  acc01 = __builtin_amdgcn_mfma_f32_32x32x16_bf16(wx0a, y1, acc01, 0,0,0); \
  acc10 = __builtin_amdgcn_mfma_f32_32x32x16_bf16(wx0b, y0, acc10, 0,0,0); \
  acc11 = __builtin_amdgcn_mfma_f32_32x32x16_bf16(wx0b, y1, acc11, 0,0,0); \
  acc00 = __builtin_amdgcn_mfma_f32_32x32x16_bf16(wx1a, y2, acc00, 0,0,0); \
  acc01 = __builtin_amdgcn_mfma_f32_32x32x16_bf16(wx1a, y3, acc01, 0,0,0); \
  acc10 = __builtin_amdgcn_mfma_f32_32x32x16_bf16(wx1b, y2, acc10, 0,0,0); \
  acc11 = __builtin_amdgcn_mfma_f32_32x32x16_bf16(wx1b, y3, acc11, 0,0,0); \
  acc00 = __builtin_amdgcn_mfma_f32_32x32x16_bf16(wx2a, y4, acc00, 0,0,0); \
  acc01 = __builtin_amdgcn_mfma_f32_32x32x16_bf16(wx2a, y5, acc01, 0,0,0); \
  acc10 = __builtin_amdgcn_mfma_f32_32x32x16_bf16(wx2b, y4, acc10, 0,0,0); \
  acc11 = __builtin_amdgcn_mfma_f32_32x32x16_bf16(wx2b, y5, acc11, 0,0,0); \
  acc00 = __builtin_amdgcn_mfma_f32_32x32x16_bf16(wx3a, y6, acc00, 0,0,0); \
  acc01 = __builtin_amdgcn_mfma_f32_32x32x16_bf16(wx3a, y7, acc01, 0,0,0); \
  acc10 = __builtin_amdgcn_mfma_f32_32x32x16_bf16(wx3b, y6, acc10, 0,0,0); \
  acc11 = __builtin_amdgcn_mfma_f32_32x32x16_bf16(wx3b, y7, acc11, 0,0,0); \
  __builtin_amdgcn_s_setprio(0); }

  for (int hc = 0; hc < 4; ++hc) {
    floatx16 acc00, acc01, acc10, acc11;   // [ht][jt]
    #pragma unroll
    for (int r = 0; r < 16; ++r) { acc00[r]=0.f; acc01[r]=0.f; acc10[r]=0.f; acc11[r]=0.f; }

    // wave w owns h tiles htg = hc*8 + w*2 (+0,+1); 48 kc16 per ht
    const unsigned short* w1p0 = w1mF + (((size_t)((hc*8 + w*2)*48)) << 9) + (lane << 3);
    const unsigned short* w1p1 = w1p0 + ((size_t)48 << 9);

    ushort8 caN0, caN1;
    floatx4 avN0, avN1, avN2, avN3;
    ushort8 wx0a, wx1a, wx2a, wx3a, wx0b, wx1b, wx2b, wx3b;

    // prologue: stage round 0 into buf0; wx(0)
    LOADCA(0); LOADAV(0);
    PACKW2(0);
    LOADWX8(0);
    __syncthreads();

    #pragma unroll
    for (int r = 0; r < 12; ++r) {
      const int cur = r & 1, nxt = cur ^ 1;
      if (r < 11) { LOADCA(r+1); LOADAV(r+1); }   // consumed late this round
      MFMA16(cur);                                 // consumes wx(r) loaded last round
      if (r < 11) {
        PACKW2(nxt);                               // write A(r+1) (covered by MFMA16)
        LOADWX8(r+1);                              // wx for next round
      }
      __syncthreads();
    }

    // ---- epilogue per ht: tanh in-register -> GEMM2 (zero shuffle) ----
    #pragma unroll
    for (int ht = 0; ht < 2; ++ht) {
      int htg = hc*8 + w*2 + ht;
      const unsigned short* w2p = w2F2 + (((size_t)(htg*2)) << 9) + (lane << 3);
      ushort8 wf0 = *reinterpret_cast<const ushort8*>(w2p);
      ushort8 wf1 = *reinterpret_cast<const ushort8*>(w2p + 512);
      int hbase = htg*32 + 4*hi5;
      #pragma unroll
      for (int jt = 0; jt < 2; ++jt) {
        const floatx16& a = (ht==0) ? (jt==0 ? acc00 : acc01)
                                    : (jt==0 ? acc10 : acc11);
        floatx16& a2 = (jt==0) ? acc2_0 : acc2_1;
        const float* qrow = Q + (size_t)(bN + jh*64 + jt*32 + col32)*HIDc + hbase;
        unsigned hfu[2][4];
        #pragma unroll
        for (int q = 0; q < 4; ++q) {
          floatx4 qv = *reinterpret_cast<const floatx4*>(qrow + 8*q);
          floatx4 pf = *reinterpret_cast<const floatx4*>(&Pi_lds[hbase + 8*q]);
          float t0 = tanh_fast(a[q*4+0] + pf[0] + qv[0]);
          float t1 = tanh_fast(a[q*4+1] + pf[1] + qv[1]);
          float t2 = tanh_fast(a[q*4+2] + pf[2] + qv[2]);
          float t3 = tanh_fast(a[q*4+3] + pf[3] + qv[3]);
          hfu[q >> 1][(q & 1)*2 + 0] = cvt_pk(t0, t1);
          hfu[q >> 1][(q & 1)*2 + 1] = cvt_pk(t2, t3);
        }
        union { uint4v u; short8 s; } f0, f1;
        f0.u[0]=hfu[0][0]; f0.u[1]=hfu[0][1]; f0.u[2]=hfu[0][2]; f0.u[3]=hfu[0][3];
        f1.u[0]=hfu[1][0]; f1.u[1]=hfu[1][1]; f1.u[2]=hfu[1][2]; f1.u[3]=hfu[1][3];
        a2 = __builtin_amdgcn_mfma_f32_32x32x16_bf16(wf0, f0.s, a2, 0,0,0);
        a2 = __builtin_amdgcn_mfma_f32_32x32x16_bf16(wf1, f1.s, a2, 0,0,0);
      }
    }
  }
#undef LOADCA
#undef LOADAV
#undef PACKW2
#undef LOADWX8
#undef MFMA16

  // ---- cross-wave reduction (only regs 0..7 carry L<16) ----
  #pragma unroll
  for (int q = 0; q < 2; ++q) {
    floatx4 v0 = { acc2_0[q*4+0], acc2_0[q*4+1], acc2_0[q*4+2], acc2_0[q*4+3] };
    floatx4 v1 = { acc2_1[q*4+0], acc2_1[q*4+1], acc2_1[q*4+2], acc2_1[q*4+3] };
    *reinterpret_cast<floatx4*>(&red[(w*2 + 0)*2 + q][lane][0]) = v0;
    *reinterpret_cast<floatx4*>(&red[(w*2 + 1)*2 + q][lane][0]) = v1;
  }
  __syncthreads();
  {
    int jtR = w & 1, qR = w >> 1;
    floatx4 s = {0.f,0.f,0.f,0.f};
    #pragma unroll
    for (int src = 0; src < 4; ++src) {
      floatx4 v = *reinterpret_cast<const floatx4*>(&red[(src*2 + jtR)*2 + qR][lane][0]);
      s[0]+=v[0]; s[1]+=v[1]; s[2]+=v[2]; s[3]+=v[3];
    }
    int jout = jh*64 + jtR*32 + col32;
    int Lb = 8*qR + 4*hi5;
    float* op = out + ((size_t)bi*Nc + jout)*Lc + Lb;
    #pragma unroll
    for (int c = 0; c < 4; ++c) op[c] = s[c] + b2v[Lb + c];
  }
}

extern "C" void kernel_launch(void* const* d_in, const int* in_sizes, int n_in,
                              void* d_out, int out_size, void* d_ws, size_t ws_size,
                              hipStream_t stream) {
  const float* AH = (const float*)d_in[0];
  const int*   ST = (const int*)d_in[1];
  const float* W1 = (const float*)d_in[2];
  const float* b1 = (const float*)d_in[3];
  const float* W2 = (const float*)d_in[4];
  const float* b2 = (const float*)d_in[5];
  float* out = (float*)d_out;

  char* ws = (char*)d_ws;
  unsigned short* con  = (unsigned short*)ws;                //   786,432 B
  unsigned short* w1mF = (unsigned short*)(ws +   786432);   // 1,572,864 B
  unsigned short* wPQF = (unsigned short*)(ws +  2359296);   // 3,145,728 B
  float* P = (float*)(ws + 5505024);                         // 2,097,152 B
  float* Q = (float*)(ws + 7602176);                         // 2,097,152 B
  unsigned short* w2F2 = (unsigned short*)(ws + 9699328);    //    65,536 B

  k_prep<<<1680, 256, 0, stream>>>(AH, ST, W1, W2, con, w1mF, w2F2, wPQF);
  k_pq<<<256, 256, 0, stream>>>(con, wPQF, P, Q);
  k_main<<<1024, 256, 0, stream>>>(con, w1mF, w2F2, P, Q, b1, b2, out);
}

// Round 12
// 151.658 us; speedup vs baseline: 1.0443x; 1.0443x over previous
//
#include <hip/hip_runtime.h>
#include <hip/hip_bf16.h>

typedef __attribute__((ext_vector_type(8))) short short8;
typedef __attribute__((ext_vector_type(8))) unsigned short ushort8;
typedef __attribute__((ext_vector_type(4))) float floatx4;
typedef __attribute__((ext_vector_type(16))) float floatx16;
typedef __attribute__((ext_vector_type(4))) unsigned int uint4v;
typedef __attribute__((ext_vector_type(2))) unsigned int uint2v;

#define DEVINL static __device__ __forceinline__

DEVINL float b2f(unsigned short s){ union{unsigned u; float f;} v; v.u=((unsigned)s)<<16; return v.f; }
DEVINL unsigned fbits(float f){ union{float f; unsigned u;} v; v.f=f; return v.u; }
DEVINL unsigned pack2(float f0, float f1){
  return __builtin_amdgcn_perm(fbits(f1)+0x8000u, fbits(f0)+0x8000u, 0x07060302u);
}
// single-instruction packed cvt (RNE), gfx950
DEVINL unsigned cvt_pk(float lo, float hi){
  unsigned r;
  asm("v_cvt_pk_bf16_f32 %0, %1, %2" : "=v"(r) : "v"(lo), "v"(hi));
  return r;
}
// tanh(x) = 1 - 2/(1+e^{2x}); exact limits at +-inf
DEVINL float tanh_fast(float v){
  float ex = __builtin_amdgcn_exp2f(v * 2.885390081777927f);   // e^{2v}
  return 1.f - 2.f*__builtin_amdgcn_rcpf(1.f + ex);
}

constexpr int Sc=256, Hc=768, Nc=128, HIDc=1024, Lc=16;

// ================= merged prep kernel =================
__global__ __launch_bounds__(256) void k_prep(const float* __restrict__ AH,
                                              const int* __restrict__ ST,
                                              const float* __restrict__ W1,
                                              const float* __restrict__ W2,
                                              unsigned short* __restrict__ con,
                                              unsigned short* __restrict__ w1mF,
                                              unsigned short* __restrict__ w2F2,
                                              unsigned short* __restrict__ wPQF){
  int bid = blockIdx.x, t = threadIdx.x;
  if (bid < 512) {
    int row = bid;                      // b*128 + n
    int b = row >> 7;
    int st = ST[row];
    const float* src = AH + ((size_t)(b*Sc + st))*Hc;
    unsigned short* dst = con + (size_t)row*Hc;
    if (t < 192) {
      float4 v = reinterpret_cast<const float4*>(src)[t];
      uint2v o = { pack2(v.x, v.y), pack2(v.z, v.w) };
      *reinterpret_cast<uint2v*>(dst + 4*t) = o;
    }
  } else if (bid < 896) {
    int sid = (bid - 512)*256 + t;      // 0..98303
    int l = sid & 63, kc = (sid >> 6) % 48, ht = sid / (48*64);
    int k = kc*16 + (l >> 5)*8;
    int h = ht*32 + (l & 31);
    const float* wp = W1 + (size_t)(2304 + k)*1024 + h;
    uint4v d;
    d[0] = pack2(wp[0],      wp[1024]);
    d[1] = pack2(wp[2*1024], wp[3*1024]);
    d[2] = pack2(wp[4*1024], wp[5*1024]);
    d[3] = pack2(wp[6*1024], wp[7*1024]);
    *reinterpret_cast<uint4v*>(w1mF + (size_t)sid*8) = d;
  } else if (bid < 912) {
    int gid = (bid - 896)*256 + t;      // 0..4095
    int l = gid & 63, chunk = gid >> 6;
    int row = l & 31, s = l >> 5;
    unsigned u[4];
    #pragma unroll
    for (int p = 0; p < 4; ++p) {
      int e0 = 2*p, e1 = 2*p + 1;
      int h0 = chunk*16 + 4*s + (e0 & 3) + 8*(e0 >> 2);
      int h1 = chunk*16 + 4*s + (e1 & 3) + 8*(e1 >> 2);
      float v0 = (row < 16) ? W2[(size_t)h0*Lc + row] : 0.f;
      float v1 = (row < 16) ? W2[(size_t)h1*Lc + row] : 0.f;
      u[p] = pack2(v0, v1);
    }
    uint4v d = { u[0], u[1], u[2], u[3] };
    *reinterpret_cast<uint4v*>(w2F2 + (size_t)gid*8) = d;
  } else {
    int sid = (bid - 912)*256 + t;      // 0..196607
    int lane = sid & 63, kcq = (sid >> 6) % 24, ht = sid / (24*64);
    int col = lane & 15, seg = lane >> 4;
    int hp = ht*16 + col;
    int kb = kcq*32 + seg*8;
    uint4v d;
    if (hp < 1024) {
      const float* w0 = W1 + (size_t)kb*1024 + hp;
      const float* wd = W1 + (size_t)(1536+kb)*1024 + hp;
      d[0] = pack2(w0[0]+wd[0],           w0[1024]+wd[1024]);
      d[1] = pack2(w0[2*1024]+wd[2*1024], w0[3*1024]+wd[3*1024]);
      d[2] = pack2(w0[4*1024]+wd[4*1024], w0[5*1024]+wd[5*1024]);
      d[3] = pack2(w0[6*1024]+wd[6*1024], w0[7*1024]+wd[7*1024]);
    } else {
      int hq = hp - 1024;
      const float* wc = W1 + (size_t)(768+kb)*1024 + hq;
      const float* wd = W1 + (size_t)(1536+kb)*1024 + hq;
      d[0] = pack2(wc[0]-wd[0],           wc[1024]-wd[1024]);
      d[1] = pack2(wc[2*1024]-wd[2*1024], wc[3*1024]-wd[3*1024]);
      d[2] = pack2(wc[4*1024]-wd[4*1024], wc[5*1024]-wd[5*1024]);
      d[3] = pack2(wc[6*1024]-wd[6*1024], wc[7*1024]-wd[7*1024]);
    }
    *reinterpret_cast<uint4v*>(wPQF + (size_t)sid*8) = d;
  }
}

// ---------------- P/Q via MFMA: out[512 rows][2048 cols] ----------------
__global__ __launch_bounds__(256) void k_pq(const unsigned short* __restrict__ con,
                                            const unsigned short* __restrict__ wPQF,
                                            float* __restrict__ P, float* __restrict__ Q){
  int rg = blockIdx.x >> 4, hg = blockIdx.x & 15;     // 16 rowgroups x 16 colgroups
  int t = threadIdx.x, w = t >> 6, lane = t & 63;
  int colh = lane & 15, rseg = lane >> 4;
  floatx4 zero = {0.f,0.f,0.f,0.f};
  floatx4 acc[2][2] = {{zero,zero},{zero,zero}};
  const unsigned short* a0p = con + (size_t)(rg*32 + colh)*Hc + rseg*8;
  const unsigned short* a1p = a0p + 16*Hc;
  const unsigned short* b0p = wPQF + (((size_t)((hg*8 + w*2)*24)) << 9) + (lane << 3);
  const unsigned short* b1p = b0p + (24 << 9);
  #pragma unroll
  for (int kc = 0; kc < 24; ++kc) {
    short8 af0 = *reinterpret_cast<const short8*>(a0p + kc*32);
    short8 af1 = *reinterpret_cast<const short8*>(a1p + kc*32);
    short8 bf0 = *reinterpret_cast<const short8*>(b0p + ((size_t)kc << 9));
    short8 bf1 = *reinterpret_cast<const short8*>(b1p + ((size_t)kc << 9));
    acc[0][0] = __builtin_amdgcn_mfma_f32_16x16x32_bf16(af0, bf0, acc[0][0], 0,0,0);
    acc[0][1] = __builtin_amdgcn_mfma_f32_16x16x32_bf16(af0, bf1, acc[0][1], 0,0,0);
    acc[1][0] = __builtin_amdgcn_mfma_f32_16x16x32_bf16(af1, bf0, acc[1][0], 0,0,0);
    acc[1][1] = __builtin_amdgcn_mfma_f32_16x16x32_bf16(af1, bf1, acc[1][1], 0,0,0);
  }
  #pragma unroll
  for (int m = 0; m < 2; ++m)
    #pragma unroll
    for (int n = 0; n < 2; ++n)
      #pragma unroll
      for (int rr = 0; rr < 4; ++rr) {
        int row = rg*32 + m*16 + rseg*4 + rr;
        int hp = hg*128 + w*32 + n*16 + colh;
        float val = acc[m][n][rr];
        if (hg < 8) P[(size_t)row*HIDc + hp] = val;
        else        Q[(size_t)row*HIDc + (hp - 1024)] = val;
      }
}

// ---------------- fused main kernel: one block per (b,i,jhalf) ----------------
// 1024 blocks x 512 threads (8 waves, 1 block/CU, 2 waves/SIMD).
// conF = a(i) .* con[j] fragments for ALL 768 k staged ONCE in 96KB LDS.
// K-loop: NO barriers, NO ds_writes, NO pack VALU: per kc16 per wave:
//   4 global wx (own-XCD L2) + 2 ds_read (static conF) + 8 MFMA.
// Wave owns 128h x 64j -> acc 8x f32x16 (128 AGPR); hc loop eliminated;
// epilogue (tanh -> reg-order GEMM2) runs ONCE; Q read once.
__global__ __launch_bounds__(512, 2) void k_main(const unsigned short* __restrict__ con,
    const unsigned short* __restrict__ w1mF, const unsigned short* __restrict__ w2F2,
    const float* __restrict__ P, const float* __restrict__ Q, const float* __restrict__ b1,
    const float* __restrict__ b2v, float* __restrict__ out){
  __shared__ __align__(16) unsigned short conF[2*48*64*8];   // 96KB [jt][kc][lane][e]
  __shared__ float Pi_lds[1024];

  // XCD-bijective decode: 8 XCDs each own one (b,jh)
  int bid = blockIdx.x;
  int xcd = bid & 7, i = bid >> 3;
  int b = xcd >> 1, jh = xcd & 1;
  int bi = b*128 + i, bN = b*128;
  int t = threadIdx.x, w = t >> 6, lane = t & 63;
  int col32 = lane & 31, hi5 = lane >> 5;

  // ---- stage Pi = P[i] + b1 (once) ----
  if (t < 256) {
    float4 p4 = reinterpret_cast<const float4*>(P + (size_t)(bN + i)*HIDc)[t];
    float4 b4 = reinterpret_cast<const float4*>(b1)[t];
    float4 s4 = { p4.x + b4.x, p4.y + b4.y, p4.z + b4.z, p4.w + b4.w };
    *reinterpret_cast<float4*>(&Pi_lds[4*t]) = s4;
  }
  // ---- stage conF once: 12 slots of 16B per thread ----
  {
    const unsigned short* conI = con + (size_t)(bN + i)*Hc;
    #pragma unroll
    for (int r = 0; r < 12; ++r) {
      int s = r*512 + t;                    // 0..6143
      int jt = (s >= 3072) ? 1 : 0;
      int rem = s - jt*3072;
      int kc = rem >> 6, ln = rem & 63;
      int j = jh*64 + jt*32 + (ln & 31);
      int kb = kc*16 + ((ln >> 5) << 3);
      ushort8 c8 = *reinterpret_cast<const ushort8*>(con + (size_t)(bN + j)*Hc + kb);
      ushort8 a8 = *reinterpret_cast<const ushort8*>(conI + kb);
      uint4v d;
      d[0] = cvt_pk(b2f(a8[0])*b2f(c8[0]), b2f(a8[1])*b2f(c8[1]));
      d[1] = cvt_pk(b2f(a8[2])*b2f(c8[2]), b2f(a8[3])*b2f(c8[3]));
      d[2] = cvt_pk(b2f(a8[4])*b2f(c8[4]), b2f(a8[5])*b2f(c8[5]));
      d[3] = cvt_pk(b2f(a8[6])*b2f(c8[6]), b2f(a8[7])*b2f(c8[7]));
      *reinterpret_cast<uint4v*>(conF + (size_t)s*8) = d;
    }
  }
  __syncthreads();

  // ---- barrier-free K loop ----
  // wave w owns ht tiles w*4 .. w*4+3 (h = htg*32 + (l&31))
  const unsigned short* wp = w1mF + (((size_t)(w*4)*48) << 9) + (lane << 3);
  const unsigned short* yb = conF + (lane << 3);
  constexpr size_t HTS = (size_t)48 << 9;   // ht stride (elems)
  constexpr size_t KCS = (size_t)1 << 9;    // kc stride (elems)
  constexpr size_t JTS = (size_t)48 << 9;   // conF jt stride

  floatx16 a0j0, a0j1, a1j0, a1j1, a2j0, a2j1, a3j0, a3j1;
  #pragma unroll
  for (int r = 0; r < 16; ++r) {
    a0j0[r]=0.f; a0j1[r]=0.f; a1j0[r]=0.f; a1j1[r]=0.f;
    a2j0[r]=0.f; a2j1[r]=0.f; a3j0[r]=0.f; a3j1[r]=0.f;
  }

#define LOADSET(W0,W1,W2,W3,Y0,Y1, KC) { \
  W0 = *reinterpret_cast<const ushort8*>(wp + (0*HTS) + (size_t)(KC)*KCS); \
  W1 = *reinterpret_cast<const ushort8*>(wp + (1*HTS) + (size_t)(KC)*KCS); \
  W2 = *reinterpret_cast<const ushort8*>(wp + (2*HTS) + (size_t)(KC)*KCS); \
  W3 = *reinterpret_cast<const ushort8*>(wp + (3*HTS) + (size_t)(KC)*KCS); \
  Y0 = *reinterpret_cast<const short8*>(yb + (size_t)(KC)*KCS); \
  Y1 = *reinterpret_cast<const short8*>(yb + JTS + (size_t)(KC)*KCS); }

#define MFMA8S(W0,W1,W2,W3,Y0,Y1) { \
  a0j0 = __builtin_amdgcn_mfma_f32_32x32x16_bf16(W0, Y0, a0j0, 0,0,0); \
  a0j1 = __builtin_amdgcn_mfma_f32_32x32x16_bf16(W0, Y1, a0j1, 0,0,0); \
  a1j0 = __builtin_amdgcn_mfma_f32_32x32x16_bf16(W1, Y0, a1j0, 0,0,0); \
  a1j1 = __builtin_amdgcn_mfma_f32_32x32x16_bf16(W1, Y1, a1j1, 0,0,0); \
  a2j0 = __builtin_amdgcn_mfma_f32_32x32x16_bf16(W2, Y0, a2j0, 0,0,0); \
  a2j1 = __builtin_amdgcn_mfma_f32_32x32x16_bf16(W2, Y1, a2j1, 0,0,0); \
  a3j0 = __builtin_amdgcn_mfma_f32_32x32x16_bf16(W3, Y0, a3j0, 0,0,0); \
  a3j1 = __builtin_amdgcn_mfma_f32_32x32x16_bf16(W3, Y1, a3j1, 0,0,0); }

  {
    ushort8 wA0,wA1,wA2,wA3, wB0,wB1,wB2,wB3;
    short8 yA0,yA1, yB0,yB1;
    LOADSET(wA0,wA1,wA2,wA3,yA0,yA1, 0);
    #pragma unroll
    for (int kp = 0; kp < 24; ++kp) {
      LOADSET(wB0,wB1,wB2,wB3,yB0,yB1, 2*kp+1);
      MFMA8S(wA0,wA1,wA2,wA3,yA0,yA1);
      if (kp < 23) LOADSET(wA0,wA1,wA2,wA3,yA0,yA1, 2*kp+2);
      MFMA8S(wB0,wB1,wB2,wB3,yB0,yB1);
    }
  }
#undef LOADSET
#undef MFMA8S

  // ---- epilogue: tanh in-register -> GEMM2 (zero shuffle), once ----
  floatx16 acc2_0, acc2_1;
  #pragma unroll
  for (int r = 0; r < 16; ++r) { acc2_0[r] = 0.f; acc2_1[r] = 0.f; }

#define EPI(M, AJ0, AJ1) { \
  int htg = w*4 + (M); \
  const unsigned short* w2p = w2F2 + (((size_t)(htg*2)) << 9) + (lane << 3); \
  ushort8 wf0 = *reinterpret_cast<const ushort8*>(w2p); \
  ushort8 wf1 = *reinterpret_cast<const ushort8*>(w2p + 512); \
  int hbase = htg*32 + 4*hi5; \
  _Pragma("unroll") \
  for (int jt = 0; jt < 2; ++jt) { \
    const floatx16& a = (jt==0) ? AJ0 : AJ1; \
    floatx16& a2 = (jt==0) ? acc2_0 : acc2_1; \
    const float* qrow = Q + (size_t)(bN + jh*64 + jt*32 + col32)*HIDc + hbase; \
    unsigned hfu[2][4]; \
    _Pragma("unroll") \
    for (int q = 0; q < 4; ++q) { \
      floatx4 qv = *reinterpret_cast<const floatx4*>(qrow + 8*q); \
      floatx4 pf = *reinterpret_cast<const floatx4*>(&Pi_lds[hbase + 8*q]); \
      float t0 = tanh_fast(a[q*4+0] + pf[0] + qv[0]); \
      float t1 = tanh_fast(a[q*4+1] + pf[1] + qv[1]); \
      float t2 = tanh_fast(a[q*4+2] + pf[2] + qv[2]); \
      float t3 = tanh_fast(a[q*4+3] + pf[3] + qv[3]); \
      hfu[q >> 1][(q & 1)*2 + 0] = cvt_pk(t0, t1); \
      hfu[q >> 1][(q & 1)*2 + 1] = cvt_pk(t2, t3); \
    } \
    union { uint4v u; short8 s; } f0, f1; \
    f0.u[0]=hfu[0][0]; f0.u[1]=hfu[0][1]; f0.u[2]=hfu[0][2]; f0.u[3]=hfu[0][3]; \
    f1.u[0]=hfu[1][0]; f1.u[1]=hfu[1][1]; f1.u[2]=hfu[1][2]; f1.u[3]=hfu[1][3]; \
    a2 = __builtin_amdgcn_mfma_f32_32x32x16_bf16(wf0, f0.s, a2, 0,0,0); \
    a2 = __builtin_amdgcn_mfma_f32_32x32x16_bf16(wf1, f1.s, a2, 0,0,0); \
  } }

  EPI(0, a0j0, a0j1);
  EPI(1, a1j0, a1j1);
  EPI(2, a2j0, a2j1);
  EPI(3, a3j0, a3j1);
#undef EPI

  // ---- cross-wave reduction (reuse conF as 32KB red buffer) ----
  __syncthreads();                       // all conF reads done
  float* red = reinterpret_cast<float*>(conF);   // [32][64][4]: row = w*4 + jt*2 + q
  #pragma unroll
  for (int q = 0; q < 2; ++q) {
    floatx4 v0 = { acc2_0[q*4+0], acc2_0[q*4+1], acc2_0[q*4+2], acc2_0[q*4+3] };
    floatx4 v1 = { acc2_1[q*4+0], acc2_1[q*4+1], acc2_1[q*4+2], acc2_1[q*4+3] };
    *reinterpret_cast<floatx4*>(&red[((w*4 + 0*2 + q)*64 + lane)*4]) = v0;
    *reinterpret_cast<floatx4*>(&red[((w*4 + 1*2 + q)*64 + lane)*4]) = v1;
  }
  __syncthreads();
  if (w < 4) {
    int jtR = w & 1, qR = w >> 1;
    floatx4 s = {0.f,0.f,0.f,0.f};
    #pragma unroll
    for (int src = 0; src < 8; ++src) {
      floatx4 v = *reinterpret_cast<const floatx4*>(&red[((src*4 + jtR*2 + qR)*64 + lane)*4]);
      s[0]+=v[0]; s[1]+=v[1]; s[2]+=v[2]; s[3]+=v[3];
    }
    int jout = jh*64 + jtR*32 + col32;
    int Lb = 8*qR + 4*hi5;
    float* op = out + ((size_t)bi*Nc + jout)*Lc + Lb;
    #pragma unroll
    for (int c = 0; c < 4; ++c) op[c] = s[c] + b2v[Lb + c];
  }
}

extern "C" void kernel_launch(void* const* d_in, const int* in_sizes, int n_in,
                              void* d_out, int out_size, void* d_ws, size_t ws_size,
                              hipStream_t stream) {
  const float* AH = (const float*)d_in[0];
  const int*   ST = (const int*)d_in[1];
  const float* W1 = (const float*)d_in[2];
  const float* b1 = (const float*)d_in[3];
  const float* W2 = (const float*)d_in[4];
  const float* b2 = (const float*)d_in[5];
  float* out = (float*)d_out;

  char* ws = (char*)d_ws;
  unsigned short* con  = (unsigned short*)ws;                //   786,432 B
  unsigned short* w1mF = (unsigned short*)(ws +   786432);   // 1,572,864 B
  unsigned short* wPQF = (unsigned short*)(ws +  2359296);   // 3,145,728 B
  float* P = (float*)(ws + 5505024);                         // 2,097,152 B
  float* Q = (float*)(ws + 7602176);                         // 2,097,152 B
  unsigned short* w2F2 = (unsigned short*)(ws + 9699328);    //    65,536 B

  k_prep<<<1680, 256, 0, stream>>>(AH, ST, W1, W2, con, w1mF, w2F2, wPQF);
  k_pq<<<256, 256, 0, stream>>>(con, wPQF, P, Q);
  k_main<<<1024, 512, 0, stream>>>(con, w1mF, w2F2, P, Q, b1, b2, out);
}

// Round 13
// 147.523 us; speedup vs baseline: 1.0736x; 1.0280x over previous
//
#include <hip/hip_runtime.h>
#include <hip/hip_bf16.h>

typedef __attribute__((ext_vector_type(8))) short short8;
typedef __attribute__((ext_vector_type(8))) unsigned short ushort8;
typedef __attribute__((ext_vector_type(4))) float floatx4;
typedef __attribute__((ext_vector_type(16))) float floatx16;
typedef __attribute__((ext_vector_type(4))) unsigned int uint4v;
typedef __attribute__((ext_vector_type(2))) unsigned int uint2v;

#define DEVINL static __device__ __forceinline__

DEVINL float b2f(unsigned short s){ union{unsigned u; float f;} v; v.u=((unsigned)s)<<16; return v.f; }
DEVINL unsigned fbits(float f){ union{float f; unsigned u;} v; v.f=f; return v.u; }
DEVINL unsigned pack2(float f0, float f1){
  return __builtin_amdgcn_perm(fbits(f1)+0x8000u, fbits(f0)+0x8000u, 0x07060302u);
}
// single-instruction packed cvt (RNE), gfx950
DEVINL unsigned cvt_pk(float lo, float hi){
  unsigned r;
  asm("v_cvt_pk_bf16_f32 %0, %1, %2" : "=v"(r) : "v"(lo), "v"(hi));
  return r;
}
// tanh(x) = 1 - 2/(1+e^{2x}); exact limits at +-inf
DEVINL float tanh_fast(float v){
  float ex = __builtin_amdgcn_exp2f(v * 2.885390081777927f);   // e^{2v}
  return 1.f - 2.f*__builtin_amdgcn_rcpf(1.f + ex);
}

constexpr int Sc=256, Hc=768, Nc=128, HIDc=1024, Lc=16;

// ================= merged prep kernel =================
__global__ __launch_bounds__(256) void k_prep(const float* __restrict__ AH,
                                              const int* __restrict__ ST,
                                              const float* __restrict__ W1,
                                              const float* __restrict__ W2,
                                              unsigned short* __restrict__ con,
                                              unsigned short* __restrict__ w1mF,
                                              unsigned short* __restrict__ w2F2,
                                              unsigned short* __restrict__ wPQF){
  int bid = blockIdx.x, t = threadIdx.x;
  if (bid < 512) {
    int row = bid;                      // b*128 + n
    int b = row >> 7;
    int st = ST[row];
    const float* src = AH + ((size_t)(b*Sc + st))*Hc;
    unsigned short* dst = con + (size_t)row*Hc;
    if (t < 192) {
      float4 v = reinterpret_cast<const float4*>(src)[t];
      uint2v o = { pack2(v.x, v.y), pack2(v.z, v.w) };
      *reinterpret_cast<uint2v*>(dst + 4*t) = o;
    }
  } else if (bid < 896) {
    int sid = (bid - 512)*256 + t;      // 0..98303
    int l = sid & 63, kc = (sid >> 6) % 48, ht = sid / (48*64);
    int k = kc*16 + (l >> 5)*8;
    int h = ht*32 + (l & 31);
    const float* wp = W1 + (size_t)(2304 + k)*1024 + h;
    uint4v d;
    d[0] = pack2(wp[0],      wp[1024]);
    d[1] = pack2(wp[2*1024], wp[3*1024]);
    d[2] = pack2(wp[4*1024], wp[5*1024]);
    d[3] = pack2(wp[6*1024], wp[7*1024]);
    *reinterpret_cast<uint4v*>(w1mF + (size_t)sid*8) = d;
  } else if (bid < 912) {
    int gid = (bid - 896)*256 + t;      // 0..4095
    int l = gid & 63, chunk = gid >> 6;
    int row = l & 31, s = l >> 5;
    unsigned u[4];
    #pragma unroll
    for (int p = 0; p < 4; ++p) {
      int e0 = 2*p, e1 = 2*p + 1;
      int h0 = chunk*16 + 4*s + (e0 & 3) + 8*(e0 >> 2);
      int h1 = chunk*16 + 4*s + (e1 & 3) + 8*(e1 >> 2);
      float v0 = (row < 16) ? W2[(size_t)h0*Lc + row] : 0.f;
      float v1 = (row < 16) ? W2[(size_t)h1*Lc + row] : 0.f;
      u[p] = pack2(v0, v1);
    }
    uint4v d = { u[0], u[1], u[2], u[3] };
    *reinterpret_cast<uint4v*>(w2F2 + (size_t)gid*8) = d;
  } else {
    int sid = (bid - 912)*256 + t;      // 0..196607
    int lane = sid & 63, kcq = (sid >> 6) % 24, ht = sid / (24*64);
    int col = lane & 15, seg = lane >> 4;
    int hp = ht*16 + col;
    int kb = kcq*32 + seg*8;
    uint4v d;
    if (hp < 1024) {
      const float* w0 = W1 + (size_t)kb*1024 + hp;
      const float* wd = W1 + (size_t)(1536+kb)*1024 + hp;
      d[0] = pack2(w0[0]+wd[0],           w0[1024]+wd[1024]);
      d[1] = pack2(w0[2*1024]+wd[2*1024], w0[3*1024]+wd[3*1024]);
      d[2] = pack2(w0[4*1024]+wd[4*1024], w0[5*1024]+wd[5*1024]);
      d[3] = pack2(w0[6*1024]+wd[6*1024], w0[7*1024]+wd[7*1024]);
    } else {
      int hq = hp - 1024;
      const float* wc = W1 + (size_t)(768+kb)*1024 + hq;
      const float* wd = W1 + (size_t)(1536+kb)*1024 + hq;
      d[0] = pack2(wc[0]-wd[0],           wc[1024]-wd[1024]);
      d[1] = pack2(wc[2*1024]-wd[2*1024], wc[3*1024]-wd[3*1024]);
      d[2] = pack2(wc[4*1024]-wd[4*1024], wc[5*1024]-wd[5*1024]);
      d[3] = pack2(wc[6*1024]-wd[6*1024], wc[7*1024]-wd[7*1024]);
    }
    *reinterpret_cast<uint4v*>(wPQF + (size_t)sid*8) = d;
  }
}

// ---------------- P/Q via MFMA: out[512 rows][2048 cols] ----------------
__global__ __launch_bounds__(256) void k_pq(const unsigned short* __restrict__ con,
                                            const unsigned short* __restrict__ wPQF,
                                            float* __restrict__ P, float* __restrict__ Q){
  int rg = blockIdx.x >> 4, hg = blockIdx.x & 15;     // 16 rowgroups x 16 colgroups
  int t = threadIdx.x, w = t >> 6, lane = t & 63;
  int colh = lane & 15, rseg = lane >> 4;
  floatx4 zero = {0.f,0.f,0.f,0.f};
  floatx4 acc[2][2] = {{zero,zero},{zero,zero}};
  const unsigned short* a0p = con + (size_t)(rg*32 + colh)*Hc + rseg*8;
  const unsigned short* a1p = a0p + 16*Hc;
  const unsigned short* b0p = wPQF + (((size_t)((hg*8 + w*2)*24)) << 9) + (lane << 3);
  const unsigned short* b1p = b0p + (24 << 9);
  #pragma unroll
  for (int kc = 0; kc < 24; ++kc) {
    short8 af0 = *reinterpret_cast<const short8*>(a0p + kc*32);
    short8 af1 = *reinterpret_cast<const short8*>(a1p + kc*32);
    short8 bf0 = *reinterpret_cast<const short8*>(b0p + ((size_t)kc << 9));
    short8 bf1 = *reinterpret_cast<const short8*>(b1p + ((size_t)kc << 9));
    acc[0][0] = __builtin_amdgcn_mfma_f32_16x16x32_bf16(af0, bf0, acc[0][0], 0,0,0);
    acc[0][1] = __builtin_amdgcn_mfma_f32_16x16x32_bf16(af0, bf1, acc[0][1], 0,0,0);
    acc[1][0] = __builtin_amdgcn_mfma_f32_16x16x32_bf16(af1, bf0, acc[1][0], 0,0,0);
    acc[1][1] = __builtin_amdgcn_mfma_f32_16x16x32_bf16(af1, bf1, acc[1][1], 0,0,0);
  }
  #pragma unroll
  for (int m = 0; m < 2; ++m)
    #pragma unroll
    for (int n = 0; n < 2; ++n)
      #pragma unroll
      for (int rr = 0; rr < 4; ++rr) {
        int row = rg*32 + m*16 + rseg*4 + rr;
        int hp = hg*128 + w*32 + n*16 + colh;
        float val = acc[m][n][rr];
        if (hg < 8) P[(size_t)row*HIDc + hp] = val;
        else        Q[(size_t)row*HIDc + (hp - 1024)] = val;
      }
}

// ---------------- fused main kernel: one block per (b,i,jhalf) ----------------
// r12 barrier-free structure + DEEP PIPELINE: wx prefetched 3 kc-steps ahead
// (4 rotating named register sets), y (LDS) 1 step ahead (2 sets), setprio(1)
// around each 8-MFMA cluster (independent-wave regime).
__global__ __launch_bounds__(512, 2) void k_main(const unsigned short* __restrict__ con,
    const unsigned short* __restrict__ w1mF, const unsigned short* __restrict__ w2F2,
    const float* __restrict__ P, const float* __restrict__ Q, const float* __restrict__ b1,
    const float* __restrict__ b2v, float* __restrict__ out){
  __shared__ __align__(16) unsigned short conF[2*48*64*8];   // 96KB [jt][kc][lane][e]
  __shared__ float Pi_lds[1024];

  // XCD-bijective decode: 8 XCDs each own one (b,jh)
  int bid = blockIdx.x;
  int xcd = bid & 7, i = bid >> 3;
  int b = xcd >> 1, jh = xcd & 1;
  int bi = b*128 + i, bN = b*128;
  int t = threadIdx.x, w = t >> 6, lane = t & 63;
  int col32 = lane & 31, hi5 = lane >> 5;

  // ---- stage Pi = P[i] + b1 (once) ----
  if (t < 256) {
    float4 p4 = reinterpret_cast<const float4*>(P + (size_t)(bN + i)*HIDc)[t];
    float4 b4 = reinterpret_cast<const float4*>(b1)[t];
    float4 s4 = { p4.x + b4.x, p4.y + b4.y, p4.z + b4.z, p4.w + b4.w };
    *reinterpret_cast<float4*>(&Pi_lds[4*t]) = s4;
  }
  // ---- stage conF once: 12 slots of 16B per thread ----
  {
    const unsigned short* conI = con + (size_t)(bN + i)*Hc;
    #pragma unroll
    for (int r = 0; r < 12; ++r) {
      int s = r*512 + t;                    // 0..6143
      int jt = (s >= 3072) ? 1 : 0;
      int rem = s - jt*3072;
      int kc = rem >> 6, ln = rem & 63;
      int j = jh*64 + jt*32 + (ln & 31);
      int kb = kc*16 + ((ln >> 5) << 3);
      ushort8 c8 = *reinterpret_cast<const ushort8*>(con + (size_t)(bN + j)*Hc + kb);
      ushort8 a8 = *reinterpret_cast<const ushort8*>(conI + kb);
      uint4v d;
      d[0] = cvt_pk(b2f(a8[0])*b2f(c8[0]), b2f(a8[1])*b2f(c8[1]));
      d[1] = cvt_pk(b2f(a8[2])*b2f(c8[2]), b2f(a8[3])*b2f(c8[3]));
      d[2] = cvt_pk(b2f(a8[4])*b2f(c8[4]), b2f(a8[5])*b2f(c8[5]));
      d[3] = cvt_pk(b2f(a8[6])*b2f(c8[6]), b2f(a8[7])*b2f(c8[7]));
      *reinterpret_cast<uint4v*>(conF + (size_t)s*8) = d;
    }
  }
  __syncthreads();

  // ---- barrier-free K loop, deep-pipelined ----
  // wave w owns ht tiles w*4 .. w*4+3 (h = htg*32 + (l&31))
  const unsigned short* wp = w1mF + (((size_t)(w*4)*48) << 9) + (lane << 3);
  const unsigned short* yb = conF + (lane << 3);
  constexpr size_t HTS = (size_t)48 << 9;   // ht stride (elems)
  constexpr size_t KCS = (size_t)1 << 9;    // kc stride (elems)
  constexpr size_t JTS = (size_t)48 << 9;   // conF jt stride

  floatx16 a0j0, a0j1, a1j0, a1j1, a2j0, a2j1, a3j0, a3j1;
  #pragma unroll
  for (int r = 0; r < 16; ++r) {
    a0j0[r]=0.f; a0j1[r]=0.f; a1j0[r]=0.f; a1j1[r]=0.f;
    a2j0[r]=0.f; a2j1[r]=0.f; a3j0[r]=0.f; a3j1[r]=0.f;
  }

#define KCL(K) ((K) < 48 ? (K) : 47)
#define LOADW(P0,P1,P2,P3, KC) { \
  size_t o_ = (size_t)KCL(KC)*KCS; \
  P0 = *reinterpret_cast<const ushort8*>(wp + 0*HTS + o_); \
  P1 = *reinterpret_cast<const ushort8*>(wp + 1*HTS + o_); \
  P2 = *reinterpret_cast<const ushort8*>(wp + 2*HTS + o_); \
  P3 = *reinterpret_cast<const ushort8*>(wp + 3*HTS + o_); }
#define LOADY(Y0,Y1, KC) { \
  size_t o_ = (size_t)KCL(KC)*KCS; \
  Y0 = *reinterpret_cast<const short8*>(yb + o_); \
  Y1 = *reinterpret_cast<const short8*>(yb + JTS + o_); }
// one k-step: prefetch W(s+3) into free W-set, Y(s+1) into other Y-set, MFMA(s)
#define STEP(U0,U1,U2,U3, Z0,Z1, PW0,PW1,PW2,PW3, PY0,PY1, KW, KY) { \
  LOADW(PW0,PW1,PW2,PW3, KW); \
  LOADY(PY0,PY1, KY); \
  __builtin_amdgcn_s_setprio(1); \
  a0j0 = __builtin_amdgcn_mfma_f32_32x32x16_bf16(U0, Z0, a0j0, 0,0,0); \
  a0j1 = __builtin_amdgcn_mfma_f32_32x32x16_bf16(U0, Z1, a0j1, 0,0,0); \
  a1j0 = __builtin_amdgcn_mfma_f32_32x32x16_bf16(U1, Z0, a1j0, 0,0,0); \
  a1j1 = __builtin_amdgcn_mfma_f32_32x32x16_bf16(U1, Z1, a1j1, 0,0,0); \
  a2j0 = __builtin_amdgcn_mfma_f32_32x32x16_bf16(U2, Z0, a2j0, 0,0,0); \
  a2j1 = __builtin_amdgcn_mfma_f32_32x32x16_bf16(U2, Z1, a2j1, 0,0,0); \
  a3j0 = __builtin_amdgcn_mfma_f32_32x32x16_bf16(U3, Z0, a3j0, 0,0,0); \
  a3j1 = __builtin_amdgcn_mfma_f32_32x32x16_bf16(U3, Z1, a3j1, 0,0,0); \
  __builtin_amdgcn_s_setprio(0); }

  {
    ushort8 wa0,wa1,wa2,wa3, wb0,wb1,wb2,wb3, wc0,wc1,wc2,wc3, wd0,wd1,wd2,wd3;
    short8 ya0,ya1, yb0,yb1;
    LOADW(wa0,wa1,wa2,wa3, 0);
    LOADW(wb0,wb1,wb2,wb3, 1);
    LOADW(wc0,wc1,wc2,wc3, 2);
    LOADY(ya0,ya1, 0);
    for (int m = 0; m < 12; ++m) {
      int s = 4*m;
      STEP(wa0,wa1,wa2,wa3, ya0,ya1, wd0,wd1,wd2,wd3, yb0,yb1, s+3, s+1);
      STEP(wb0,wb1,wb2,wb3, yb0,yb1, wa0,wa1,wa2,wa3, ya0,ya1, s+4, s+2);
      STEP(wc0,wc1,wc2,wc3, ya0,ya1, wb0,wb1,wb2,wb3, yb0,yb1, s+5, s+3);
      STEP(wd0,wd1,wd2,wd3, yb0,yb1, wc0,wc1,wc2,wc3, ya0,ya1, s+6, s+4);
    }
  }
#undef KCL
#undef LOADW
#undef LOADY
#undef STEP

  // ---- epilogue: tanh in-register -> GEMM2 (zero shuffle), once ----
  floatx16 acc2_0, acc2_1;
  #pragma unroll
  for (int r = 0; r < 16; ++r) { acc2_0[r] = 0.f; acc2_1[r] = 0.f; }

#define EPI(M, AJ0, AJ1) { \
  int htg = w*4 + (M); \
  const unsigned short* w2p = w2F2 + (((size_t)(htg*2)) << 9) + (lane << 3); \
  ushort8 wf0 = *reinterpret_cast<const ushort8*>(w2p); \
  ushort8 wf1 = *reinterpret_cast<const ushort8*>(w2p + 512); \
  int hbase = htg*32 + 4*hi5; \
  _Pragma("unroll") \
  for (int jt = 0; jt < 2; ++jt) { \
    const floatx16& a = (jt==0) ? AJ0 : AJ1; \
    floatx16& a2 = (jt==0) ? acc2_0 : acc2_1; \
    const float* qrow = Q + (size_t)(bN + jh*64 + jt*32 + col32)*HIDc + hbase; \
    unsigned hfu[2][4]; \
    _Pragma("unroll") \
    for (int q = 0; q < 4; ++q) { \
      floatx4 qv = *reinterpret_cast<const floatx4*>(qrow + 8*q); \
      floatx4 pf = *reinterpret_cast<const floatx4*>(&Pi_lds[hbase + 8*q]); \
      float t0 = tanh_fast(a[q*4+0] + pf[0] + qv[0]); \
      float t1 = tanh_fast(a[q*4+1] + pf[1] + qv[1]); \
      float t2 = tanh_fast(a[q*4+2] + pf[2] + qv[2]); \
      float t3 = tanh_fast(a[q*4+3] + pf[3] + qv[3]); \
      hfu[q >> 1][(q & 1)*2 + 0] = cvt_pk(t0, t1); \
      hfu[q >> 1][(q & 1)*2 + 1] = cvt_pk(t2, t3); \
    } \
    union { uint4v u; short8 s; } f0, f1; \
    f0.u[0]=hfu[0][0]; f0.u[1]=hfu[0][1]; f0.u[2]=hfu[0][2]; f0.u[3]=hfu[0][3]; \
    f1.u[0]=hfu[1][0]; f1.u[1]=hfu[1][1]; f1.u[2]=hfu[1][2]; f1.u[3]=hfu[1][3]; \
    a2 = __builtin_amdgcn_mfma_f32_32x32x16_bf16(wf0, f0.s, a2, 0,0,0); \
    a2 = __builtin_amdgcn_mfma_f32_32x32x16_bf16(wf1, f1.s, a2, 0,0,0); \
  } }

  EPI(0, a0j0, a0j1);
  EPI(1, a1j0, a1j1);
  EPI(2, a2j0, a2j1);
  EPI(3, a3j0, a3j1);
#undef EPI

  // ---- cross-wave reduction (reuse conF as 32KB red buffer) ----
  __syncthreads();                       // all conF reads done
  float* red = reinterpret_cast<float*>(conF);   // [32][64][4]: row = w*4 + jt*2 + q
  #pragma unroll
  for (int q = 0; q < 2; ++q) {
    floatx4 v0 = { acc2_0[q*4+0], acc2_0[q*4+1], acc2_0[q*4+2], acc2_0[q*4+3] };
    floatx4 v1 = { acc2_1[q*4+0], acc2_1[q*4+1], acc2_1[q*4+2], acc2_1[q*4+3] };
    *reinterpret_cast<floatx4*>(&red[((w*4 + 0*2 + q)*64 + lane)*4]) = v0;
    *reinterpret_cast<floatx4*>(&red[((w*4 + 1*2 + q)*64 + lane)*4]) = v1;
  }
  __syncthreads();
  if (w < 4) {
    int jtR = w & 1, qR = w >> 1;
    floatx4 s = {0.f,0.f,0.f,0.f};
    #pragma unroll
    for (int src = 0; src < 8; ++src) {
      floatx4 v = *reinterpret_cast<const floatx4*>(&red[((src*4 + jtR*2 + qR)*64 + lane)*4]);
      s[0]+=v[0]; s[1]+=v[1]; s[2]+=v[2]; s[3]+=v[3];
    }
    int jout = jh*64 + jtR*32 + col32;
    int Lb = 8*qR + 4*hi5;
    float* op = out + ((size_t)bi*Nc + jout)*Lc + Lb;
    #pragma unroll
    for (int c = 0; c < 4; ++c) op[c] = s[c] + b2v[Lb + c];
  }
}

extern "C" void kernel_launch(void* const* d_in, const int* in_sizes, int n_in,
                              void* d_out, int out_size, void* d_ws, size_t ws_size,
                              hipStream_t stream) {
  const float* AH = (const float*)d_in[0];
  const int*   ST = (const int*)d_in[1];
  const float* W1 = (const float*)d_in[2];
  const float* b1 = (const float*)d_in[3];
  const float* W2 = (const float*)d_in[4];
  const float* b2 = (const float*)d_in[5];
  float* out = (float*)d_out;

  char* ws = (char*)d_ws;
  unsigned short* con  = (unsigned short*)ws;                //   786,432 B
  unsigned short* w1mF = (unsigned short*)(ws +   786432);   // 1,572,864 B
  unsigned short* wPQF = (unsigned short*)(ws +  2359296);   // 3,145,728 B
  float* P = (float*)(ws + 5505024);                         // 2,097,152 B
  float* Q = (float*)(ws + 7602176);                         // 2,097,152 B
  unsigned short* w2F2 = (unsigned short*)(ws + 9699328);    //    65,536 B

  k_prep<<<1680, 256, 0, stream>>>(AH, ST, W1, W2, con, w1mF, w2F2, wPQF);
  k_pq<<<256, 256, 0, stream>>>(con, wPQF, P, Q);
  k_main<<<1024, 512, 0, stream>>>(con, w1mF, w2F2, P, Q, b1, b2, out);
}